// Round 9
// baseline (192.969 us; speedup 1.0000x reference)
//
#include <hip/hip_runtime.h>

#define S    512
#define OUT  512
#define NB   8
#define CB   32
#define TRW  16                      // rows per wave
#define NBLK (NB * CB * 8)           // 256 planes * 8 blocks/plane = 2048

// ---------------------------------------------------------------------------
// Kernel 1 (v3, unchanged): wave-per-row inverse-CDF coords, register-resident.
// ---------------------------------------------------------------------------
__global__ __launch_bounds__(64) void coords_kernel(
    const float* __restrict__ attx, const float* __restrict__ atty,
    int2* __restrict__ coords)               // [2][8][512]
{
  __shared__ double sc[S];
  const int lane = threadIdx.x;              // 0..63
  const int n    = blockIdx.x & 7;
  const int axis = blockIdx.x >> 3;
  const float* att = (axis == 0 ? attx : atty) + n * S;

  double a[8];
#pragma unroll
  for (int k = 0; k < 8; ++k) a[k] = (double)att[lane * 8 + k];

  double tot = 0.0;
#pragma unroll
  for (int k = 0; k < 8; ++k) tot += a[k];
#pragma unroll
  for (int off = 32; off > 0; off >>= 1) tot += __shfl_xor(tot, off);

#pragma unroll
  for (int k = 0; k < 8; ++k) a[k] = a[k] / tot * (double)OUT;
  const double thr = (double)(4 * OUT) / (double)S;   // = 4.0

  for (int it = 0; it < 5; ++it) {
    double s = 0.0;
#pragma unroll
    for (int k = 0; k < 8; ++k) { a[k] = a[k] < thr ? a[k] : thr; s += a[k]; }
#pragma unroll
    for (int off = 32; off > 0; off >>= 1) s += __shfl_xor(s, off);
    const double corr = ((double)OUT - s) / (double)S;
#pragma unroll
    for (int k = 0; k < 8; ++k) a[k] += corr;
  }

  double p[8]; double run = 0.0;
#pragma unroll
  for (int k = 0; k < 8; ++k) { run += a[k]; p[k] = run; }
  double v = run;
#pragma unroll
  for (int off = 1; off < 64; off <<= 1) {
    double t = __shfl_up(v, off);
    if (lane >= off) v += t;
  }
  const double excl = v - run;
#pragma unroll
  for (int k = 0; k < 8; ++k) sc[lane * 8 + k] = excl + p[k];
  __syncthreads();

  const double step = sc[S - 1] / (double)OUT;

#pragma unroll
  for (int k = 0; k < 8; ++k) {
    const int ox = lane * 8 + k;
    const double tgt = step * (double)(ox + 1);

    int lo = 0, hi = S;
    while (lo < hi) {
      int mid = (lo + hi) >> 1;
      if (sc[mid] < tgt) lo = mid + 1; else hi = mid;
    }
    int j = lo < S - 1 ? lo : S - 1;

    double right = sc[j];
    double left  = (j > 0) ? sc[j - 1] : 0.0;
    double denom = right - left;
    if (denom < 1e-8) denom = 1e-8;
    double frac = (tgt - left) / denom;
    frac = frac < 0.0 ? 0.0 : (frac > 1.0 ? 1.0 : frac);

    double pp  = ((double)j + frac) / (double)S * (double)(S - 1);
    double p0f = floor(pp);
    double w   = pp - p0f;
    int i0 = (int)p0f;
    i0 = i0 < 0 ? 0 : (i0 > S - 1 ? S - 1 : i0);

    coords[(axis * NB + n) * S + ox] = make_int2(i0, __float_as_int((float)w));
  }
}

// ---------------------------------------------------------------------------
// Kernel 2 (v9 = v8 sliding window + two-slot register prefetch pipeline):
// loads for row r+2's new input row(s) are issued at step r, so each load has
// ~2 rows of compute+store (plus TLP) to cover HBM latency, while keeping the
// sliding window's minimal (~0.9 rows/output-row) read traffic and nt stores.
// Fully unrolled so all slot indices are compile-time (no scratch).
// Transition types (wave-uniform): 0 same rows, 1 advance-by-one (only the
// new B row is loaded; CxA <- CxB in registers), 2 jump (both rows loaded).
// ---------------------------------------------------------------------------
__global__ __launch_bounds__(256) void sample_kernel(
    const float* __restrict__ data, const int2* __restrict__ coords,
    float* __restrict__ out)
{
  __shared__ float bufA_[4][S + 1];
  __shared__ float bufB_[4][S + 1];

  int b = (int)blockIdx.x;
  b = (b & 7) * (NBLK / 8) + (b >> 3);       // bijective XCD swizzle
  const int plane = b >> 3;                  // n*CB + c
  const int bip   = b & 7;
  const int n     = plane >> 5;

  const int tid  = threadIdx.x;
  const int wv   = tid >> 6;
  const int lane = tid & 63;
  const int oy0  = bip * 64 + wv * TRW;

  const float* __restrict__ pl = data + (size_t)plane * (S * S);
  float* __restrict__       po = out  + (size_t)plane * (S * S);

  // hoisted x coords: lane handles ox = lane + 64k
  int   ix[8];
  float wx[8];
#pragma unroll
  for (int k = 0; k < 8; ++k) {
    const int2 cx = coords[n * S + lane + 64 * k];
    ix[k] = cx.x;
    wx[k] = __int_as_float(cx.y);
  }

  float* bufA = bufA_[wv];
  float* bufB = bufB_[wv];
  const int2* __restrict__ cyp = coords + (NB + n) * S + oy0;

  float CxA[8], CxB[8];
  float4 qA0[2], qA1[2], qB0[2], qB1[2];     // two prefetch slots
  int   ttype[2];
  float wys[2];
  int prevA;

  // ---- prologue: issue slot 0 (row 0, always jump) ----
  {
    const int2 c = cyp[0];
    const int a = c.x;
    wys[0] = __int_as_float(c.y);
    const int rb = (a + 1 < S) ? a + 1 : S - 1;
    const float4* RA = (const float4*)(pl + (size_t)a  * S);
    const float4* RB = (const float4*)(pl + (size_t)rb * S);
    qA0[0] = RA[lane]; qA1[0] = RA[lane + 64];
    qB0[0] = RB[lane]; qB1[0] = RB[lane + 64];
    ttype[0] = 2;
    prevA = a;
  }
  // ---- prologue: issue slot 1 (row 1) ----
  {
    const int2 c = cyp[1];
    const int a = c.x;
    wys[1] = __int_as_float(c.y);
    if (a == prevA) {
      ttype[1] = 0;
    } else {
      const int rb = (a + 1 < S) ? a + 1 : S - 1;
      const float4* RB = (const float4*)(pl + (size_t)rb * S);
      qB0[1] = RB[lane]; qB1[1] = RB[lane + 64];
      if (a == prevA + 1) {
        ttype[1] = 1;
      } else {
        const float4* RA = (const float4*)(pl + (size_t)a * S);
        qA0[1] = RA[lane]; qA1[1] = RA[lane + 64];
        ttype[1] = 2;
      }
      prevA = a;
    }
  }

#pragma unroll
  for (int r = 0; r < TRW; ++r) {
    const int s = r & 1;
    const int t = ttype[s];
    const float wy = wys[s];

    // 1) commit slot s's row(s) to wave-private LDS
    if (t == 2) {
      ((float4*)bufA)[lane]      = qA0[s];
      ((float4*)bufA)[lane + 64] = qA1[s];
      ((float4*)bufB)[lane]      = qB0[s];
      ((float4*)bufB)[lane + 64] = qB1[s];
      if (lane == 63) { bufA[S] = qA1[s].w; bufB[S] = qB1[s].w; }
    } else if (t == 1) {
      ((float4*)bufB)[lane]      = qB0[s];
      ((float4*)bufB)[lane + 64] = qB1[s];
      if (lane == 63) bufB[S] = qB1[s].w;
    }

    // 2) issue prefetch for row r+2 into slot s (regs now free)
    if (r + 2 < TRW) {
      const int2 c = cyp[r + 2];
      const int a = c.x;
      wys[s] = __int_as_float(c.y);
      if (a == prevA) {
        ttype[s] = 0;
      } else {
        const int rb = (a + 1 < S) ? a + 1 : S - 1;
        const float4* RB = (const float4*)(pl + (size_t)rb * S);
        qB0[s] = RB[lane]; qB1[s] = RB[lane + 64];
        if (a == prevA + 1) {
          ttype[s] = 1;
        } else {
          const float4* RA = (const float4*)(pl + (size_t)a * S);
          qA0[s] = RA[lane]; qA1[s] = RA[lane + 64];
          ttype[s] = 2;
        }
        prevA = a;
      }
    }

    // 3) gather along x from LDS, y-lerp, nontemporal store
    if (t == 2) {
#pragma unroll
      for (int k = 0; k < 8; ++k) {
        const float x0 = bufA[ix[k]];
        const float x1 = bufA[ix[k] + 1];
        CxA[k] = x0 + wx[k] * (x1 - x0);
      }
#pragma unroll
      for (int k = 0; k < 8; ++k) {
        const float x0 = bufB[ix[k]];
        const float x1 = bufB[ix[k] + 1];
        CxB[k] = x0 + wx[k] * (x1 - x0);
      }
    } else if (t == 1) {
#pragma unroll
      for (int k = 0; k < 8; ++k) CxA[k] = CxB[k];
#pragma unroll
      for (int k = 0; k < 8; ++k) {
        const float x0 = bufB[ix[k]];
        const float x1 = bufB[ix[k] + 1];
        CxB[k] = x0 + wx[k] * (x1 - x0);
      }
    }

    float* orow = po + (size_t)(oy0 + r) * OUT;
#pragma unroll
    for (int k = 0; k < 8; ++k)
      __builtin_nontemporal_store(CxA[k] + wy * (CxB[k] - CxA[k]),
                                  orow + lane + 64 * k);
  }
}

extern "C" void kernel_launch(void* const* d_in, const int* in_sizes, int n_in,
                              void* d_out, int out_size, void* d_ws, size_t ws_size,
                              hipStream_t stream) {
  const float* data = (const float*)d_in[0];
  const float* attx = (const float*)d_in[1];
  const float* atty = (const float*)d_in[2];
  float* out = (float*)d_out;

  // Workspace: int2 coords[2][8][512]  (x coords then y coords), 64 KB
  int2* coords = (int2*)d_ws;

  coords_kernel<<<16, 64, 0, stream>>>(attx, atty, coords);

  sample_kernel<<<NBLK, 256, 0, stream>>>(data, coords, out);
}

// Round 10
// 99.916 us; speedup vs baseline: 1.9313x; 1.9313x over previous
//
#include <hip/hip_runtime.h>

#define S    512
#define OUT  512
#define NB   8
#define CB   32
#define TRW  8                       // rows per wave (finer granularity)
#define NBLK (NB * CB * 16)          // 256 planes * 16 blocks/plane = 4096

// ---------------------------------------------------------------------------
// Kernel 1 (v3, unchanged): wave-per-row inverse-CDF coords, register-resident.
// ---------------------------------------------------------------------------
__global__ __launch_bounds__(64) void coords_kernel(
    const float* __restrict__ attx, const float* __restrict__ atty,
    int2* __restrict__ coords)               // [2][8][512]
{
  __shared__ double sc[S];
  const int lane = threadIdx.x;              // 0..63
  const int n    = blockIdx.x & 7;
  const int axis = blockIdx.x >> 3;
  const float* att = (axis == 0 ? attx : atty) + n * S;

  double a[8];
#pragma unroll
  for (int k = 0; k < 8; ++k) a[k] = (double)att[lane * 8 + k];

  double tot = 0.0;
#pragma unroll
  for (int k = 0; k < 8; ++k) tot += a[k];
#pragma unroll
  for (int off = 32; off > 0; off >>= 1) tot += __shfl_xor(tot, off);

#pragma unroll
  for (int k = 0; k < 8; ++k) a[k] = a[k] / tot * (double)OUT;
  const double thr = (double)(4 * OUT) / (double)S;   // = 4.0

  for (int it = 0; it < 5; ++it) {
    double s = 0.0;
#pragma unroll
    for (int k = 0; k < 8; ++k) { a[k] = a[k] < thr ? a[k] : thr; s += a[k]; }
#pragma unroll
    for (int off = 32; off > 0; off >>= 1) s += __shfl_xor(s, off);
    const double corr = ((double)OUT - s) / (double)S;
#pragma unroll
    for (int k = 0; k < 8; ++k) a[k] += corr;
  }

  double p[8]; double run = 0.0;
#pragma unroll
  for (int k = 0; k < 8; ++k) { run += a[k]; p[k] = run; }
  double v = run;
#pragma unroll
  for (int off = 1; off < 64; off <<= 1) {
    double t = __shfl_up(v, off);
    if (lane >= off) v += t;
  }
  const double excl = v - run;
#pragma unroll
  for (int k = 0; k < 8; ++k) sc[lane * 8 + k] = excl + p[k];
  __syncthreads();

  const double step = sc[S - 1] / (double)OUT;

#pragma unroll
  for (int k = 0; k < 8; ++k) {
    const int ox = lane * 8 + k;
    const double tgt = step * (double)(ox + 1);

    int lo = 0, hi = S;
    while (lo < hi) {
      int mid = (lo + hi) >> 1;
      if (sc[mid] < tgt) lo = mid + 1; else hi = mid;
    }
    int j = lo < S - 1 ? lo : S - 1;

    double right = sc[j];
    double left  = (j > 0) ? sc[j - 1] : 0.0;
    double denom = right - left;
    if (denom < 1e-8) denom = 1e-8;
    double frac = (tgt - left) / denom;
    frac = frac < 0.0 ? 0.0 : (frac > 1.0 ? 1.0 : frac);

    double pp  = ((double)j + frac) / (double)S * (double)(S - 1);
    double p0f = floor(pp);
    double w   = pp - p0f;
    int i0 = (int)p0f;
    i0 = i0 < 0 ? 0 : (i0 > S - 1 ? S - 1 : i0);

    coords[(axis * NB + n) * S + ox] = make_int2(i0, __float_as_int((float)w));
  }
}

// ---------------------------------------------------------------------------
// Kernel 2 (v10 = v8 verbatim, TRW 16->8, NBLK 2048->4096): sliding-window
// Cx reuse, barrier-free, wave-private, nontemporal output stores. Finer
// block granularity (16 blocks/CU avg) lets the HW scheduler rebalance the
// up-to-4x per-stripe load variance that left v8 at 69% measured occupancy.
// ---------------------------------------------------------------------------
__global__ __launch_bounds__(256) void sample_kernel(
    const float* __restrict__ data, const int2* __restrict__ coords,
    float* __restrict__ out)
{
  __shared__ float bufA_[4][S + 1];
  __shared__ float bufB_[4][S + 1];

  int b = (int)blockIdx.x;
  b = (b & 7) * (NBLK / 8) + (b >> 3);       // bijective XCD swizzle
  const int plane = b >> 4;                  // n*CB + c
  const int bip   = b & 15;                  // block-in-plane (16 stripes)
  const int n     = plane >> 5;

  const int tid  = threadIdx.x;
  const int wv   = tid >> 6;
  const int lane = tid & 63;
  const int oy0  = bip * (4 * TRW) + wv * TRW;

  const float* __restrict__ pl = data + (size_t)plane * (S * S);
  float* __restrict__       po = out  + (size_t)plane * (S * S);

  // hoisted x coords: lane handles ox = lane + 64k
  int   ix[8];
  float wx[8];
#pragma unroll
  for (int k = 0; k < 8; ++k) {
    const int2 cx = coords[n * S + lane + 64 * k];
    ix[k] = cx.x;
    wx[k] = __int_as_float(cx.y);
  }

  float* bufA = bufA_[wv];
  float* bufB = bufB_[wv];
  const int2* __restrict__ cyp = coords + (NB + n) * S + oy0;

  float CxA[8], CxB[8];
  int curA = -1000;                          // forces jump path at r=0

  for (int r = 0; r < TRW; ++r) {
    const int2 cy = cyp[r];                  // wave-uniform
    const int   a  = cy.x;
    const float wy = __int_as_float(cy.y);

    if (a != curA) {
      const int rowB = (a + 1 < S) ? a + 1 : S - 1;
      if (a == curA + 1) {
        // +1 advance: old B row becomes new A row — shift registers
#pragma unroll
        for (int k = 0; k < 8; ++k) CxA[k] = CxB[k];
        const float4* RB = (const float4*)(pl + (size_t)rowB * S);
        const float4 p0 = RB[lane];
        const float4 p1 = RB[lane + 64];
        ((float4*)bufB)[lane]      = p0;
        ((float4*)bufB)[lane + 64] = p1;
        if (lane == 63) bufB[S] = p1.w;      // pad: clamp to last element
#pragma unroll
        for (int k = 0; k < 8; ++k) {
          const float x0 = bufB[ix[k]];
          const float x1 = bufB[ix[k] + 1];
          CxB[k] = x0 + wx[k] * (x1 - x0);
        }
      } else {
        // jump: load + stage + gather both rows (loads issue back-to-back)
        const float4* RA = (const float4*)(pl + (size_t)a    * S);
        const float4* RB = (const float4*)(pl + (size_t)rowB * S);
        const float4 q0 = RA[lane];
        const float4 q1 = RA[lane + 64];
        const float4 p0 = RB[lane];
        const float4 p1 = RB[lane + 64];
        ((float4*)bufA)[lane]      = q0;
        ((float4*)bufA)[lane + 64] = q1;
        ((float4*)bufB)[lane]      = p0;
        ((float4*)bufB)[lane + 64] = p1;
        if (lane == 63) { bufA[S] = q1.w; bufB[S] = p1.w; }
#pragma unroll
        for (int k = 0; k < 8; ++k) {
          const float x0 = bufA[ix[k]];
          const float x1 = bufA[ix[k] + 1];
          CxA[k] = x0 + wx[k] * (x1 - x0);
        }
#pragma unroll
        for (int k = 0; k < 8; ++k) {
          const float x0 = bufB[ix[k]];
          const float x1 = bufB[ix[k] + 1];
          CxB[k] = x0 + wx[k] * (x1 - x0);
        }
      }
      curA = a;
    }

    // y-lerp + coalesced NONTEMPORAL stores (wave covers the full 2 KB row)
    float* orow = po + (size_t)(oy0 + r) * OUT;
#pragma unroll
    for (int k = 0; k < 8; ++k)
      __builtin_nontemporal_store(CxA[k] + wy * (CxB[k] - CxA[k]),
                                  orow + lane + 64 * k);
  }
}

extern "C" void kernel_launch(void* const* d_in, const int* in_sizes, int n_in,
                              void* d_out, int out_size, void* d_ws, size_t ws_size,
                              hipStream_t stream) {
  const float* data = (const float*)d_in[0];
  const float* attx = (const float*)d_in[1];
  const float* atty = (const float*)d_in[2];
  float* out = (float*)d_out;

  // Workspace: int2 coords[2][8][512]  (x coords then y coords), 64 KB
  int2* coords = (int2*)d_ws;

  coords_kernel<<<16, 64, 0, stream>>>(attx, atty, coords);

  sample_kernel<<<NBLK, 256, 0, stream>>>(data, coords, out);
}

// Round 11
// 99.418 us; speedup vs baseline: 1.9410x; 1.0050x over previous
//
#include <hip/hip_runtime.h>

#define S    512
#define OUT  512
#define NB   8
#define CB   32
#define TRW  8                       // rows per wave
#define WPB  2                       // waves per block (fine dispatch grain)
#define NBLK (NB * CB * 32)          // 256 planes * 32 blocks/plane = 8192

// ---------------------------------------------------------------------------
// Kernel 1 (v3, unchanged): wave-per-row inverse-CDF coords, register-resident.
// ---------------------------------------------------------------------------
__global__ __launch_bounds__(64) void coords_kernel(
    const float* __restrict__ attx, const float* __restrict__ atty,
    int2* __restrict__ coords)               // [2][8][512]
{
  __shared__ double sc[S];
  const int lane = threadIdx.x;              // 0..63
  const int n    = blockIdx.x & 7;
  const int axis = blockIdx.x >> 3;
  const float* att = (axis == 0 ? attx : atty) + n * S;

  double a[8];
#pragma unroll
  for (int k = 0; k < 8; ++k) a[k] = (double)att[lane * 8 + k];

  double tot = 0.0;
#pragma unroll
  for (int k = 0; k < 8; ++k) tot += a[k];
#pragma unroll
  for (int off = 32; off > 0; off >>= 1) tot += __shfl_xor(tot, off);

#pragma unroll
  for (int k = 0; k < 8; ++k) a[k] = a[k] / tot * (double)OUT;
  const double thr = (double)(4 * OUT) / (double)S;   // = 4.0

  for (int it = 0; it < 5; ++it) {
    double s = 0.0;
#pragma unroll
    for (int k = 0; k < 8; ++k) { a[k] = a[k] < thr ? a[k] : thr; s += a[k]; }
#pragma unroll
    for (int off = 32; off > 0; off >>= 1) s += __shfl_xor(s, off);
    const double corr = ((double)OUT - s) / (double)S;
#pragma unroll
    for (int k = 0; k < 8; ++k) a[k] += corr;
  }

  double p[8]; double run = 0.0;
#pragma unroll
  for (int k = 0; k < 8; ++k) { run += a[k]; p[k] = run; }
  double v = run;
#pragma unroll
  for (int off = 1; off < 64; off <<= 1) {
    double t = __shfl_up(v, off);
    if (lane >= off) v += t;
  }
  const double excl = v - run;
#pragma unroll
  for (int k = 0; k < 8; ++k) sc[lane * 8 + k] = excl + p[k];
  __syncthreads();

  const double step = sc[S - 1] / (double)OUT;

#pragma unroll
  for (int k = 0; k < 8; ++k) {
    const int ox = lane * 8 + k;
    const double tgt = step * (double)(ox + 1);

    int lo = 0, hi = S;
    while (lo < hi) {
      int mid = (lo + hi) >> 1;
      if (sc[mid] < tgt) lo = mid + 1; else hi = mid;
    }
    int j = lo < S - 1 ? lo : S - 1;

    double right = sc[j];
    double left  = (j > 0) ? sc[j - 1] : 0.0;
    double denom = right - left;
    if (denom < 1e-8) denom = 1e-8;
    double frac = (tgt - left) / denom;
    frac = frac < 0.0 ? 0.0 : (frac > 1.0 ? 1.0 : frac);

    double pp  = ((double)j + frac) / (double)S * (double)(S - 1);
    double p0f = floor(pp);
    double w   = pp - p0f;
    int i0 = (int)p0f;
    i0 = i0 < 0 ? 0 : (i0 > S - 1 ? S - 1 : i0);

    coords[(axis * NB + n) * S + ox] = make_int2(i0, __float_as_int((float)w));
  }
}

// ---------------------------------------------------------------------------
// Kernel 2 (v11 = v10 with 128-thread blocks): sliding-window Cx reuse,
// barrier-free, wave-private, nontemporal stores. 2 waves/block * 8192
// blocks: up to 16 resident blocks/CU (full 32-wave TLP) with 2-wave
// dispatch granules, so dense-stripe stragglers block only a small slot
// and the HW scheduler backfills finer. Same traffic as v10 (TRW=8).
// ---------------------------------------------------------------------------
__global__ __launch_bounds__(128) void sample_kernel(
    const float* __restrict__ data, const int2* __restrict__ coords,
    float* __restrict__ out)
{
  __shared__ float bufA_[WPB][S + 1];
  __shared__ float bufB_[WPB][S + 1];

  int b = (int)blockIdx.x;
  b = (b & 7) * (NBLK / 8) + (b >> 3);       // bijective XCD swizzle
  const int plane = b >> 5;                  // n*CB + c   (32 blocks/plane)
  const int bip   = b & 31;                  // block-in-plane
  const int n     = plane >> 5;

  const int tid  = threadIdx.x;
  const int wv   = tid >> 6;                 // 0..1
  const int lane = tid & 63;
  const int oy0  = (bip * WPB + wv) * TRW;

  const float* __restrict__ pl = data + (size_t)plane * (S * S);
  float* __restrict__       po = out  + (size_t)plane * (S * S);

  // hoisted x coords: lane handles ox = lane + 64k
  int   ix[8];
  float wx[8];
#pragma unroll
  for (int k = 0; k < 8; ++k) {
    const int2 cx = coords[n * S + lane + 64 * k];
    ix[k] = cx.x;
    wx[k] = __int_as_float(cx.y);
  }

  float* bufA = bufA_[wv];
  float* bufB = bufB_[wv];
  const int2* __restrict__ cyp = coords + (NB + n) * S + oy0;

  float CxA[8], CxB[8];
  int curA = -1000;                          // forces jump path at r=0

  for (int r = 0; r < TRW; ++r) {
    const int2 cy = cyp[r];                  // wave-uniform
    const int   a  = cy.x;
    const float wy = __int_as_float(cy.y);

    if (a != curA) {
      const int rowB = (a + 1 < S) ? a + 1 : S - 1;
      if (a == curA + 1) {
        // +1 advance: old B row becomes new A row — shift registers
#pragma unroll
        for (int k = 0; k < 8; ++k) CxA[k] = CxB[k];
        const float4* RB = (const float4*)(pl + (size_t)rowB * S);
        const float4 p0 = RB[lane];
        const float4 p1 = RB[lane + 64];
        ((float4*)bufB)[lane]      = p0;
        ((float4*)bufB)[lane + 64] = p1;
        if (lane == 63) bufB[S] = p1.w;      // pad: clamp to last element
#pragma unroll
        for (int k = 0; k < 8; ++k) {
          const float x0 = bufB[ix[k]];
          const float x1 = bufB[ix[k] + 1];
          CxB[k] = x0 + wx[k] * (x1 - x0);
        }
      } else {
        // jump: load + stage + gather both rows (loads issue back-to-back)
        const float4* RA = (const float4*)(pl + (size_t)a    * S);
        const float4* RB = (const float4*)(pl + (size_t)rowB * S);
        const float4 q0 = RA[lane];
        const float4 q1 = RA[lane + 64];
        const float4 p0 = RB[lane];
        const float4 p1 = RB[lane + 64];
        ((float4*)bufA)[lane]      = q0;
        ((float4*)bufA)[lane + 64] = q1;
        ((float4*)bufB)[lane]      = p0;
        ((float4*)bufB)[lane + 64] = p1;
        if (lane == 63) { bufA[S] = q1.w; bufB[S] = p1.w; }
#pragma unroll
        for (int k = 0; k < 8; ++k) {
          const float x0 = bufA[ix[k]];
          const float x1 = bufA[ix[k] + 1];
          CxA[k] = x0 + wx[k] * (x1 - x0);
        }
#pragma unroll
        for (int k = 0; k < 8; ++k) {
          const float x0 = bufB[ix[k]];
          const float x1 = bufB[ix[k] + 1];
          CxB[k] = x0 + wx[k] * (x1 - x0);
        }
      }
      curA = a;
    }

    // y-lerp + coalesced NONTEMPORAL stores (wave covers the full 2 KB row)
    float* orow = po + (size_t)(oy0 + r) * OUT;
#pragma unroll
    for (int k = 0; k < 8; ++k)
      __builtin_nontemporal_store(CxA[k] + wy * (CxB[k] - CxA[k]),
                                  orow + lane + 64 * k);
  }
}

extern "C" void kernel_launch(void* const* d_in, const int* in_sizes, int n_in,
                              void* d_out, int out_size, void* d_ws, size_t ws_size,
                              hipStream_t stream) {
  const float* data = (const float*)d_in[0];
  const float* attx = (const float*)d_in[1];
  const float* atty = (const float*)d_in[2];
  float* out = (float*)d_out;

  // Workspace: int2 coords[2][8][512]  (x coords then y coords), 64 KB
  int2* coords = (int2*)d_ws;

  coords_kernel<<<16, 64, 0, stream>>>(attx, atty, coords);

  sample_kernel<<<NBLK, 128, 0, stream>>>(data, coords, out);
}

// Round 12
// 99.402 us; speedup vs baseline: 1.9413x; 1.0002x over previous
//
#include <hip/hip_runtime.h>

#define S    512
#define OUT  512
#define NB   8
#define CB   32
#define WPB  2                       // waves per block
#define NSPP 64                      // stripes per plane (cost-balanced)
#define NBLK (NB * CB * (NSPP / WPB))   // 256 planes * 32 blocks = 8192

// ---------------------------------------------------------------------------
// Kernel 1 (v4): wave-per-row inverse-CDF coords + cost-balanced stripe
// boundaries. 16 blocks x 64 threads; block = (axis, n). Each lane owns 8
// cells. After emitting coords, the axis==1 (y) block computes per-output-row
// staging cost (1 write + 0/1/2 staged rows), prefix-sums it, and emits 64
// equal-cost quantile boundaries per batch for the sampler's wave stripes.
// ---------------------------------------------------------------------------
__global__ __launch_bounds__(64) void coords_kernel(
    const float* __restrict__ attx, const float* __restrict__ atty,
    int2* __restrict__ coords,               // [2][8][512]
    int* __restrict__ bnd)                   // [8][65]
{
  __shared__ double sc[S];
  __shared__ int pr[S];
  const int lane = threadIdx.x;              // 0..63
  const int n    = blockIdx.x & 7;
  const int axis = blockIdx.x >> 3;
  const float* att = (axis == 0 ? attx : atty) + n * S;

  double a[8];
#pragma unroll
  for (int k = 0; k < 8; ++k) a[k] = (double)att[lane * 8 + k];

  double tot = 0.0;
#pragma unroll
  for (int k = 0; k < 8; ++k) tot += a[k];
#pragma unroll
  for (int off = 32; off > 0; off >>= 1) tot += __shfl_xor(tot, off);

#pragma unroll
  for (int k = 0; k < 8; ++k) a[k] = a[k] / tot * (double)OUT;
  const double thr = (double)(4 * OUT) / (double)S;   // = 4.0

  for (int it = 0; it < 5; ++it) {
    double s = 0.0;
#pragma unroll
    for (int k = 0; k < 8; ++k) { a[k] = a[k] < thr ? a[k] : thr; s += a[k]; }
#pragma unroll
    for (int off = 32; off > 0; off >>= 1) s += __shfl_xor(s, off);
    const double corr = ((double)OUT - s) / (double)S;
#pragma unroll
    for (int k = 0; k < 8; ++k) a[k] += corr;
  }

  double p[8]; double run = 0.0;
#pragma unroll
  for (int k = 0; k < 8; ++k) { run += a[k]; p[k] = run; }
  double v = run;
#pragma unroll
  for (int off = 1; off < 64; off <<= 1) {
    double t = __shfl_up(v, off);
    if (lane >= off) v += t;
  }
  const double excl = v - run;
#pragma unroll
  for (int k = 0; k < 8; ++k) sc[lane * 8 + k] = excl + p[k];
  __syncthreads();

  const double step = sc[S - 1] / (double)OUT;

  int i0s[8];
#pragma unroll
  for (int k = 0; k < 8; ++k) {
    const int ox = lane * 8 + k;
    const double tgt = step * (double)(ox + 1);

    int lo = 0, hi = S;
    while (lo < hi) {
      int mid = (lo + hi) >> 1;
      if (sc[mid] < tgt) lo = mid + 1; else hi = mid;
    }
    int j = lo < S - 1 ? lo : S - 1;

    double right = sc[j];
    double left  = (j > 0) ? sc[j - 1] : 0.0;
    double denom = right - left;
    if (denom < 1e-8) denom = 1e-8;
    double frac = (tgt - left) / denom;
    frac = frac < 0.0 ? 0.0 : (frac > 1.0 ? 1.0 : frac);

    double pp  = ((double)j + frac) / (double)S * (double)(S - 1);
    double p0f = floor(pp);
    double w   = pp - p0f;
    int i0 = (int)p0f;
    i0 = i0 < 0 ? 0 : (i0 > S - 1 ? S - 1 : i0);
    i0s[k] = i0;

    coords[(axis * NB + n) * S + ox] = make_int2(i0, __float_as_int((float)w));
  }

  // ---- axis==1: cost-balanced stripe boundaries for the sampler ----
  if (axis == 1) {
    const int fromPrev = __shfl_up(i0s[7], 1);
    int prevv = (lane == 0) ? (i0s[0] - 2) : fromPrev;  // oy=0 is a jump
    int cinc[8]; int runc = 0;
#pragma unroll
    for (int k = 0; k < 8; ++k) {
      const int d = i0s[k] - prevv;
      const int c = 1 + (d <= 0 ? 0 : (d == 1 ? 1 : 2));
      runc += c; cinc[k] = runc; prevv = i0s[k];
    }
    int vv = runc;
#pragma unroll
    for (int off = 1; off < 64; off <<= 1) {
      const int t = __shfl_up(vv, off);
      if (lane >= off) vv += t;
    }
    const int exclc = vv - runc;
#pragma unroll
    for (int k = 0; k < 8; ++k) pr[lane * 8 + k] = exclc + cinc[k];
    __syncthreads();

    const int Ctot = pr[S - 1];
    const int tgt = (int)(((long long)lane * Ctot) / NSPP);
    // first oy with pr[oy] > tgt
    int lo = 0, hi = S;
    while (lo < hi) {
      const int mid = (lo + hi) >> 1;
      if (pr[mid] <= tgt) lo = mid + 1; else hi = mid;
    }
    bnd[n * (NSPP + 1) + lane] = lo;
    if (lane == 63) bnd[n * (NSPP + 1) + NSPP] = S;
  }
}

// ---------------------------------------------------------------------------
// Kernel 2 (v12 = v11 with cost-balanced stripes): sliding-window Cx reuse,
// barrier-free, wave-private, nontemporal stores. Each wave's output-row
// range comes from the equal-cost boundary table, so every wave moves
// ~equal HBM bytes (fixes the 74%-occupancy drain tail of fixed stripes).
// ---------------------------------------------------------------------------
__global__ __launch_bounds__(128) void sample_kernel(
    const float* __restrict__ data, const int2* __restrict__ coords,
    const int* __restrict__ bnd, float* __restrict__ out)
{
  __shared__ float bufA_[WPB][S + 1];
  __shared__ float bufB_[WPB][S + 1];

  int b = (int)blockIdx.x;
  b = (b & 7) * (NBLK / 8) + (b >> 3);       // bijective XCD swizzle
  const int plane = b >> 5;                  // n*CB + c   (32 blocks/plane)
  const int bip   = b & 31;                  // block-in-plane
  const int n     = plane >> 5;

  const int tid  = threadIdx.x;
  const int wv   = tid >> 6;                 // 0..1
  const int lane = tid & 63;
  const int s    = bip * WPB + wv;           // stripe 0..63
  const int oy0   = bnd[n * (NSPP + 1) + s];
  const int oyend = bnd[n * (NSPP + 1) + s + 1];

  const float* __restrict__ pl = data + (size_t)plane * (S * S);
  float* __restrict__       po = out  + (size_t)plane * (S * S);

  // hoisted x coords: lane handles ox = lane + 64k
  int   ix[8];
  float wx[8];
#pragma unroll
  for (int k = 0; k < 8; ++k) {
    const int2 cx = coords[n * S + lane + 64 * k];
    ix[k] = cx.x;
    wx[k] = __int_as_float(cx.y);
  }

  float* bufA = bufA_[wv];
  float* bufB = bufB_[wv];
  const int2* __restrict__ cyp = coords + (NB + n) * S;

  float CxA[8], CxB[8];
  int curA = -1000;                          // forces jump path first

  for (int oy = oy0; oy < oyend; ++oy) {
    const int2 cy = cyp[oy];                 // wave-uniform
    const int   a  = cy.x;
    const float wy = __int_as_float(cy.y);

    if (a != curA) {
      const int rowB = (a + 1 < S) ? a + 1 : S - 1;
      if (a == curA + 1) {
        // +1 advance: old B row becomes new A row — shift registers
#pragma unroll
        for (int k = 0; k < 8; ++k) CxA[k] = CxB[k];
        const float4* RB = (const float4*)(pl + (size_t)rowB * S);
        const float4 p0 = RB[lane];
        const float4 p1 = RB[lane + 64];
        ((float4*)bufB)[lane]      = p0;
        ((float4*)bufB)[lane + 64] = p1;
        if (lane == 63) bufB[S] = p1.w;      // pad: clamp to last element
#pragma unroll
        for (int k = 0; k < 8; ++k) {
          const float x0 = bufB[ix[k]];
          const float x1 = bufB[ix[k] + 1];
          CxB[k] = x0 + wx[k] * (x1 - x0);
        }
      } else {
        // jump: load + stage + gather both rows (loads issue back-to-back)
        const float4* RA = (const float4*)(pl + (size_t)a    * S);
        const float4* RB = (const float4*)(pl + (size_t)rowB * S);
        const float4 q0 = RA[lane];
        const float4 q1 = RA[lane + 64];
        const float4 p0 = RB[lane];
        const float4 p1 = RB[lane + 64];
        ((float4*)bufA)[lane]      = q0;
        ((float4*)bufA)[lane + 64] = q1;
        ((float4*)bufB)[lane]      = p0;
        ((float4*)bufB)[lane + 64] = p1;
        if (lane == 63) { bufA[S] = q1.w; bufB[S] = p1.w; }
#pragma unroll
        for (int k = 0; k < 8; ++k) {
          const float x0 = bufA[ix[k]];
          const float x1 = bufA[ix[k] + 1];
          CxA[k] = x0 + wx[k] * (x1 - x0);
        }
#pragma unroll
        for (int k = 0; k < 8; ++k) {
          const float x0 = bufB[ix[k]];
          const float x1 = bufB[ix[k] + 1];
          CxB[k] = x0 + wx[k] * (x1 - x0);
        }
      }
      curA = a;
    }

    // y-lerp + coalesced NONTEMPORAL stores (wave covers the full 2 KB row)
    float* orow = po + (size_t)oy * OUT;
#pragma unroll
    for (int k = 0; k < 8; ++k)
      __builtin_nontemporal_store(CxA[k] + wy * (CxB[k] - CxA[k]),
                                  orow + lane + 64 * k);
  }
}

extern "C" void kernel_launch(void* const* d_in, const int* in_sizes, int n_in,
                              void* d_out, int out_size, void* d_ws, size_t ws_size,
                              hipStream_t stream) {
  const float* data = (const float*)d_in[0];
  const float* attx = (const float*)d_in[1];
  const float* atty = (const float*)d_in[2];
  float* out = (float*)d_out;

  // Workspace: int2 coords[2][8][512] (64 KB) then int bnd[8][65] (~2 KB)
  int2* coords = (int2*)d_ws;
  int*  bnd    = (int*)((char*)d_ws + 2 * NB * S * sizeof(int2));

  coords_kernel<<<16, 64, 0, stream>>>(attx, atty, coords, bnd);

  sample_kernel<<<NBLK, 128, 0, stream>>>(data, coords, bnd, out);
}